// Round 1
// baseline (519.946 us; speedup 1.0000x reference)
//
#include <hip/hip_runtime.h>

typedef _Float16 f16;
typedef f16 f16x8 __attribute__((ext_vector_type(8)));
typedef f16 f16x4 __attribute__((ext_vector_type(4)));
typedef float f32x4 __attribute__((ext_vector_type(4)));

// sizes
#define BDIM 16
#define CDIM 512
#define MDIM 4
#define NDIM 4096
#define EDIM 4
#define H1D  128
#define H2D  48
#define OUTD 16
#define NB   64          // n-columns per tile
#define NTILES (NDIM/NB) // 64

// ---------------- prep: fp32 weights -> f16 fragment layout ----------------
// W1s: [e][kb(64)][o(128)][ki(8)]  (k = kb*8+ki, K=512)
// W2s: [e][kb(16)][o(48)][ki(8)]   (K=128)
// W3s: [e][kb(8)][o(16)][ki(8)]    (K=64, zero-padded from 48)
__global__ __launch_bounds__(256) void prep_kernel(
    const float* __restrict__ W1, const float* __restrict__ W2, const float* __restrict__ W3,
    f16* __restrict__ W1s, f16* __restrict__ W2s, f16* __restrict__ W3s)
{
  int i = blockIdx.x * 256 + threadIdx.x;
  if (i < 262144) {
    int ki = i & 7; int rest = i >> 3;
    int o = rest & 127; rest >>= 7;
    int kb = rest & 63; int e = rest >> 6;
    W1s[i] = (f16)W1[(e*128 + o)*512 + kb*8 + ki];
  } else if (i < 262144 + 24576) {
    int j = i - 262144;
    int ki = j & 7; int rest = j >> 3;
    int o = rest % 48; rest /= 48;
    int kb = rest & 15; int e = rest >> 4;
    W2s[j] = (f16)W2[(e*48 + o)*128 + kb*8 + ki];
  } else if (i < 262144 + 24576 + 4096) {
    int j = i - 262144 - 24576;
    int ki = j & 7; int rest = j >> 3;
    int o = rest & 15; rest >>= 4;
    int kb = rest & 7; int e = rest >> 3;
    int k = kb*8 + ki;
    W3s[j] = (k < 48) ? (f16)W3[(e*16 + o)*48 + k] : (f16)0.f;
  }
}

// ---------------- pool: mean over n per (b,c,m) row ----------------
__global__ __launch_bounds__(256) void pool_kernel(const float* __restrict__ x,
                                                   float* __restrict__ pooled)
{
  __shared__ float red[4];
  const int tid = threadIdx.x;
  const float* row = x + (size_t)blockIdx.x * NDIM;
  float s = 0.f;
  #pragma unroll
  for (int it = 0; it < 4; ++it) {
    float4 v = *(const float4*)(row + it*1024 + tid*4);
    s += v.x + v.y + v.z + v.w;
  }
  #pragma unroll
  for (int off = 32; off; off >>= 1) s += __shfl_down(s, off);
  if ((tid & 63) == 0) red[tid >> 6] = s;
  __syncthreads();
  if (tid == 0) pooled[blockIdx.x] = (red[0]+red[1]+red[2]+red[3]) * (1.0f/4096.0f);
}

// ---------------- gate: fp32 MLP + softmax (with torch reshape quirk) ------
__global__ __launch_bounds__(256) void gate_kernel(
    const float* __restrict__ pooled, const float* __restrict__ Wg1,
    const float* __restrict__ bg1, const float* __restrict__ Wg2,
    const float* __restrict__ bg2, float* __restrict__ wgt)
{
  __shared__ float pl[512*4];   // [c][m]
  __shared__ float g1[128*4];   // [o][m]
  __shared__ float g2[16];      // [e][m]
  const int b = blockIdx.x, tid = threadIdx.x;
  for (int i = tid; i < 2048; i += 256) pl[i] = pooled[b*2048 + i];
  __syncthreads();
  #pragma unroll
  for (int u = 0; u < 2; ++u) {
    int idx = u*256 + tid;
    int o = idx >> 2, mm = idx & 3;
    float acc = bg1[o];
    for (int c = 0; c < 512; ++c) acc += Wg1[o*512 + c] * pl[c*4 + mm];
    g1[o*4 + mm] = fmaxf(acc, 0.f);
  }
  __syncthreads();
  if (tid < 16) {
    int e = tid >> 2, mm = tid & 3;
    float acc = bg2[e];
    for (int o = 0; o < 128; ++o) acc += Wg2[e*128 + o] * g1[o*4 + mm];
    g2[e*4 + mm] = acc;
  }
  __syncthreads();
  if (tid < 4) {
    // weights[b][m][e] = softmax_e over G[m][e], G[m][e] = g2[expert=m][modal=e]
    int mrow = tid;
    float v0 = g2[mrow*4+0], v1 = g2[mrow*4+1], v2 = g2[mrow*4+2], v3 = g2[mrow*4+3];
    float mx = fmaxf(fmaxf(v0,v1), fmaxf(v2,v3));
    float e0 = expf(v0-mx), e1 = expf(v1-mx), e2 = expf(v2-mx), e3 = expf(v3-mx);
    float inv = 1.0f / (e0+e1+e2+e3);
    wgt[b*16 + mrow*4 + 0] = e0*inv;
    wgt[b*16 + mrow*4 + 1] = e1*inv;
    wgt[b*16 + mrow*4 + 2] = e2*inv;
    wgt[b*16 + mrow*4 + 3] = e3*inv;
  }
}

// ---------------- fused MoE: 3-layer chain + weighted combine ----------------
// block = (b, m, tile of 64 n-columns); 512 threads = 8 waves.
// LDS: Xs [64 cblk][64 p][8 ci] f16 (64 KiB) ; H1t [16][64][8] (16 KiB) ; H2t [8][64][8] (8 KiB)
__global__ __launch_bounds__(512, 2) void moe_kernel(
    const float* __restrict__ x,
    const f16* __restrict__ W1s, const f16* __restrict__ W2s, const f16* __restrict__ W3s,
    const float* __restrict__ b1, const float* __restrict__ b2, const float* __restrict__ b3,
    const float* __restrict__ wgt, float* __restrict__ out)
{
  extern __shared__ char smem[];
  f16* Xs  = (f16*)smem;                        // 65536 B
  f16* H1t = (f16*)(smem + 65536);              // 16384 B
  f16* H2t = (f16*)(smem + 65536 + 16384);      //  8192 B

  const int tid  = threadIdx.x;
  const int bid  = blockIdx.x;
  const int tile = bid & 63;
  const int m    = (bid >> 6) & 3;
  const int b    = bid >> 8;

  // zero the K-pad of H2t (hblk 6,7 => h=48..63)
  for (int i = tid; i < 1024; i += 512) H2t[3072 + i] = (f16)0.f;

  // ---- stage X tile: fp32 global -> f16 LDS, transposed into [cblk][p][8] ----
  const size_t xbase = ((size_t)(b*2048 + m)) * 4096 + (size_t)tile*64;
  #pragma unroll 4
  for (int it = 0; it < 16; ++it) {
    int idx = it*512 + tid;
    int row = idx >> 4, q = idx & 15;              // row=c, q*4 = p0
    const float4 v = *(const float4*)(x + xbase + (size_t)row*16384 + q*4);
    int base = ((row >> 3)*64 + q*4)*8 + (row & 7);
    Xs[base]      = (f16)v.x;
    Xs[base + 8]  = (f16)v.y;
    Xs[base + 16] = (f16)v.z;
    Xs[base + 24] = (f16)v.w;
  }
  __syncthreads();

  const int wave = tid >> 6, lane = tid & 63;
  const int g = lane >> 4, r = lane & 15;
  const int o0 = wave * 16;

  f32x4 outacc = {0.f, 0.f, 0.f, 0.f};   // waves 0-3: final 16x16 out fragment

  for (int e = 0; e < 4; ++e) {
    // ---- Layer 1: H1[o][p] = relu(W1 @ X + b1), o0 = wave*16, all 4 p-tiles ----
    f32x4 acc1[4] = {{0,0,0,0},{0,0,0,0},{0,0,0,0},{0,0,0,0}};
    {
      const f16* Wbase = W1s + (size_t)e*65536 + (o0 + r)*8;
      #pragma unroll 4
      for (int ks = 0; ks < 16; ++ks) {
        int kb = ks*4 + g;
        f16x8 a = *(const f16x8*)(Wbase + kb*1024);
        #pragma unroll
        for (int pt = 0; pt < 4; ++pt) {
          f16x8 bf = *(const f16x8*)(Xs + (kb*64 + pt*16 + r)*8);
          acc1[pt] = __builtin_amdgcn_mfma_f32_16x16x32_f16(a, bf, acc1[pt], 0, 0, 0);
        }
      }
    }
    {
      const float4 bias = *(const float4*)(b1 + e*128 + o0 + g*4);
      const int hblk = wave*2 + (g >> 1), ci0 = (g & 1)*4;
      #pragma unroll
      for (int pt = 0; pt < 4; ++pt) {
        f16x4 h;
        h[0] = (f16)fmaxf(acc1[pt][0] + bias.x, 0.f);
        h[1] = (f16)fmaxf(acc1[pt][1] + bias.y, 0.f);
        h[2] = (f16)fmaxf(acc1[pt][2] + bias.z, 0.f);
        h[3] = (f16)fmaxf(acc1[pt][3] + bias.w, 0.f);
        *(f16x4*)(H1t + (hblk*64 + pt*16 + r)*8 + ci0) = h;
      }
    }
    __syncthreads();

    // ---- Layer 2: H2 = relu(W2 @ H1 + b2); 12 fragments over 8 waves ----
    #pragma unroll
    for (int s = 0; s < 2; ++s) {
      int f = wave + s*8;
      if (f < 12) {
        int ot = f >> 2, pt = f & 3;
        f32x4 acc2 = {0,0,0,0};
        #pragma unroll
        for (int ks = 0; ks < 4; ++ks) {
          int kb = ks*4 + g;
          f16x8 a  = *(const f16x8*)(W2s + ((e*16 + kb)*48 + ot*16 + r)*8);
          f16x8 bf = *(const f16x8*)(H1t + (kb*64 + pt*16 + r)*8);
          acc2 = __builtin_amdgcn_mfma_f32_16x16x32_f16(a, bf, acc2, 0, 0, 0);
        }
        const float4 bias = *(const float4*)(b2 + e*48 + ot*16 + g*4);
        const int hblk = ot*2 + (g >> 1), ci0 = (g & 1)*4;
        f16x4 h;
        h[0] = (f16)fmaxf(acc2[0] + bias.x, 0.f);
        h[1] = (f16)fmaxf(acc2[1] + bias.y, 0.f);
        h[2] = (f16)fmaxf(acc2[2] + bias.z, 0.f);
        h[3] = (f16)fmaxf(acc2[3] + bias.w, 0.f);
        *(f16x4*)(H2t + (hblk*64 + pt*16 + r)*8 + ci0) = h;
      }
    }
    __syncthreads();

    // ---- Layer 3 + weighted combine (waves 0-3, pt = wave) ----
    if (wave < 4) {
      const int pt = wave;
      f32x4 acc3 = {0,0,0,0};
      #pragma unroll
      for (int ks = 0; ks < 2; ++ks) {
        int kb = ks*4 + g;
        f16x8 a  = *(const f16x8*)(W3s + ((e*8 + kb)*16 + r)*8);
        f16x8 bf = *(const f16x8*)(H2t + (kb*64 + pt*16 + r)*8);
        acc3 = __builtin_amdgcn_mfma_f32_16x16x32_f16(a, bf, acc3, 0, 0, 0);
      }
      const float w_e = wgt[(b*4 + m)*4 + e];
      const float4 bias = *(const float4*)(b3 + e*16 + g*4);
      outacc[0] += w_e * (acc3[0] + bias.x);
      outacc[1] += w_e * (acc3[1] + bias.y);
      outacc[2] += w_e * (acc3[2] + bias.z);
      outacc[3] += w_e * (acc3[3] + bias.w);
    }
    // no barrier needed here: next L1 writes H1t only after the post-L1 barrier,
    // and all L2 reads of H1t completed before the post-L2 barrier above.
  }

  // ---- store out[b][o][m][n] ----
  if (wave < 4) {
    const int pt = wave;
    #pragma unroll
    for (int reg = 0; reg < 4; ++reg) {
      int o = g*4 + reg;
      out[(((size_t)b*16 + o)*4 + m)*4096 + (size_t)tile*64 + pt*16 + r] = outacc[reg];
    }
  }
}

// ---------------- launcher ----------------
extern "C" void kernel_launch(void* const* d_in, const int* in_sizes, int n_in,
                              void* d_out, int out_size, void* d_ws, size_t ws_size,
                              hipStream_t stream) {
  const float* x   = (const float*)d_in[0];
  const float* W1  = (const float*)d_in[1];
  const float* b1  = (const float*)d_in[2];
  const float* W2  = (const float*)d_in[3];
  const float* b2  = (const float*)d_in[4];
  const float* W3  = (const float*)d_in[5];
  const float* b3  = (const float*)d_in[6];
  const float* Wg1 = (const float*)d_in[7];
  const float* bg1 = (const float*)d_in[8];
  const float* Wg2 = (const float*)d_in[9];
  const float* bg2 = (const float*)d_in[10];
  float* out = (float*)d_out;

  char* ws = (char*)d_ws;
  float* pooled = (float*)ws;                         // 131072 B  [b][c][m]
  float* wgt    = (float*)(ws + 131072);              //   1024 B  [b][m][e]
  f16* W1s = (f16*)(ws + 132096);                     // 524288 B
  f16* W2s = (f16*)(ws + 132096 + 524288);            //  49152 B
  f16* W3s = (f16*)(ws + 132096 + 524288 + 49152);    //   8192 B

  hipFuncSetAttribute(reinterpret_cast<const void*>(moe_kernel),
                      hipFuncAttributeMaxDynamicSharedMemorySize, 90112);

  prep_kernel<<<(262144 + 24576 + 4096 + 255)/256, 256, 0, stream>>>(W1, W2, W3, W1s, W2s, W3s);
  pool_kernel<<<BDIM*CDIM*MDIM, 256, 0, stream>>>(x, pooled);
  gate_kernel<<<BDIM, 256, 0, stream>>>(pooled, Wg1, bg1, Wg2, bg2, wgt);
  moe_kernel<<<BDIM*MDIM*NTILES, 512, 90112, stream>>>(x, W1s, W2s, W3s, b1, b2, b3, wgt, out);
}

// Round 2
// 412.069 us; speedup vs baseline: 1.2618x; 1.2618x over previous
//
#include <hip/hip_runtime.h>

typedef _Float16 f16;
typedef f16 f16x8 __attribute__((ext_vector_type(8)));
typedef f16 f16x4 __attribute__((ext_vector_type(4)));
typedef f16 f16x2 __attribute__((ext_vector_type(2)));
typedef float f32x4 __attribute__((ext_vector_type(4)));

// sizes
#define BDIM 16
#define CDIM 512
#define MDIM 4
#define NDIM 4096
#define NB   64          // n-columns per tile
#define NTILES (NDIM/NB) // 64

// LDS swizzle: spreads rows p across 8 16B slots; bijective per row
#define SX(p) ((((p)&7) ^ (((p)>>3)&7)))

// ---------------- prep: fp32 weights -> f16 fragment layout ----------------
// W1s: [e][kb(64)][o(128)][ki(8)]  (k = kb*8+ki, K=512)
// W2s: [e][kb(16)][o(48)][ki(8)]   (K=128)
// W3s: [e][kb(8)][o(16)][ki(8)]    (K=64, zero-padded from 48)
__global__ __launch_bounds__(256) void prep_kernel(
    const float* __restrict__ W1, const float* __restrict__ W2, const float* __restrict__ W3,
    f16* __restrict__ W1s, f16* __restrict__ W2s, f16* __restrict__ W3s)
{
  int i = blockIdx.x * 256 + threadIdx.x;
  if (i < 262144) {
    int ki = i & 7; int rest = i >> 3;
    int o = rest & 127; rest >>= 7;
    int kb = rest & 63; int e = rest >> 6;
    W1s[i] = (f16)W1[(e*128 + o)*512 + kb*8 + ki];
  } else if (i < 262144 + 24576) {
    int j = i - 262144;
    int ki = j & 7; int rest = j >> 3;
    int o = rest % 48; rest /= 48;
    int kb = rest & 15; int e = rest >> 4;
    W2s[j] = (f16)W2[(e*48 + o)*128 + kb*8 + ki];
  } else if (i < 262144 + 24576 + 4096) {
    int j = i - 262144 - 24576;
    int ki = j & 7; int rest = j >> 3;
    int o = rest & 15; rest >>= 4;
    int kb = rest & 7; int e = rest >> 3;
    int k = kb*8 + ki;
    W3s[j] = (k < 48) ? (f16)W3[(e*16 + o)*48 + k] : (f16)0.f;
  }
}

// ---------------- pool: mean over n per (b,c,m) row ----------------
__global__ __launch_bounds__(256) void pool_kernel(const float* __restrict__ x,
                                                   float* __restrict__ pooled)
{
  __shared__ float red[4];
  const int tid = threadIdx.x;
  const float* row = x + (size_t)blockIdx.x * NDIM;
  float s = 0.f;
  #pragma unroll
  for (int it = 0; it < 4; ++it) {
    float4 v = *(const float4*)(row + it*1024 + tid*4);
    s += v.x + v.y + v.z + v.w;
  }
  #pragma unroll
  for (int off = 32; off; off >>= 1) s += __shfl_down(s, off);
  if ((tid & 63) == 0) red[tid >> 6] = s;
  __syncthreads();
  if (tid == 0) pooled[blockIdx.x] = (red[0]+red[1]+red[2]+red[3]) * (1.0f/4096.0f);
}

// ---------------- gate: fp32 MLP + softmax (with torch reshape quirk) ------
__global__ __launch_bounds__(256) void gate_kernel(
    const float* __restrict__ pooled, const float* __restrict__ Wg1,
    const float* __restrict__ bg1, const float* __restrict__ Wg2,
    const float* __restrict__ bg2, float* __restrict__ wgt)
{
  __shared__ float pl[512*4];   // [c][m]
  __shared__ float g1[128*4];   // [o][m]
  __shared__ float g2[16];      // [e][m]
  const int b = blockIdx.x, tid = threadIdx.x;
  for (int i = tid; i < 2048; i += 256) pl[i] = pooled[b*2048 + i];
  __syncthreads();
  #pragma unroll
  for (int u = 0; u < 2; ++u) {
    int idx = u*256 + tid;
    int o = idx >> 2, mm = idx & 3;
    float acc = bg1[o];
    for (int c = 0; c < 512; ++c) acc += Wg1[o*512 + c] * pl[c*4 + mm];
    g1[o*4 + mm] = fmaxf(acc, 0.f);
  }
  __syncthreads();
  if (tid < 16) {
    int e = tid >> 2, mm = tid & 3;
    float acc = bg2[e];
    for (int o = 0; o < 128; ++o) acc += Wg2[e*128 + o] * g1[o*4 + mm];
    g2[e*4 + mm] = acc;
  }
  __syncthreads();
  if (tid < 4) {
    // weights[b][m][e] = softmax_e over G[m][e], G[m][e] = g2[expert=m][modal=e]
    int mrow = tid;
    float v0 = g2[mrow*4+0], v1 = g2[mrow*4+1], v2 = g2[mrow*4+2], v3 = g2[mrow*4+3];
    float mx = fmaxf(fmaxf(v0,v1), fmaxf(v2,v3));
    float e0 = expf(v0-mx), e1 = expf(v1-mx), e2 = expf(v2-mx), e3 = expf(v3-mx);
    float inv = 1.0f / (e0+e1+e2+e3);
    wgt[b*16 + mrow*4 + 0] = e0*inv;
    wgt[b*16 + mrow*4 + 1] = e1*inv;
    wgt[b*16 + mrow*4 + 2] = e2*inv;
    wgt[b*16 + mrow*4 + 3] = e3*inv;
  }
}

// ---------------- fused MoE: 3-layer chain + weighted combine ----------------
// block = (b, m, 64 n-columns); 512 threads = 8 waves; 2 blocks/CU.
// Phase A: K-chunked (8 x 64 channels, double-buffered LDS), L1 accumulated
//          in regs for ALL 4 experts (acc[e][pt], o0 = wave*16).
// Phase B: per expert: H1->LDS, L2, L3 + weighted combine.
// LDS (40 KiB): Xs 2x[64p][128B], H1t [64p][256B], H2t [64p][128B], swizzled.
__global__ __launch_bounds__(512, 4) void moe_kernel(
    const float* __restrict__ x,
    const f16* __restrict__ W1s, const f16* __restrict__ W2s, const f16* __restrict__ W3s,
    const float* __restrict__ b1, const float* __restrict__ b2, const float* __restrict__ b3,
    const float* __restrict__ wgt, float* __restrict__ out)
{
  __shared__ __align__(16) char smem[40960];
  char* Xs0 = smem;                 //  8192 B
  char* Xs1 = smem + 8192;          //  8192 B
  char* H1t = smem + 16384;         // 16384 B
  char* H2t = smem + 32768;         //  8192 B

  const int tid  = threadIdx.x;
  const int bid  = blockIdx.x;
  const int tile = bid & 63;
  const int m    = (bid >> 6) & 3;
  const int b    = bid >> 8;

  // zero H2t once (provides the K-pad h=48..63 for all experts)
  ((uint4*)H2t)[tid] = make_uint4(0u,0u,0u,0u);

  const int wave = tid >> 6, lane = tid & 63;
  const int g = lane >> 4, r = lane & 15;
  const int o0 = wave * 16;

  // ---- staging coords: thread handles channel pair (2*cp, 2*cp+1), p-quad q*4..q*4+3
  const int cp = tid >> 4;          // 0..31
  const int q  = tid & 15;          // 0..15
  const float* xb = x + ((size_t)(b*2048 + m)) * 4096 + (size_t)tile*64
                      + (size_t)(2*cp)*16384 + q*4;

  // prologue: stage chunk 0
  {
    f32x4 v0 = *(const f32x4*)xb;
    f32x4 v1 = *(const f32x4*)(xb + 16384);
    #pragma unroll
    for (int i = 0; i < 4; ++i) {
      int p = q*4 + i;
      f16x2 hv; hv[0] = (f16)v0[i]; hv[1] = (f16)v1[i];
      *(f16x2*)(Xs0 + p*128 + ((4*cp) ^ (SX(p)<<4))) = hv;
    }
  }

  f32x4 acc[4][4];
  #pragma unroll
  for (int e = 0; e < 4; ++e)
    #pragma unroll
    for (int pt = 0; pt < 4; ++pt) acc[e][pt] = (f32x4){0.f,0.f,0.f,0.f};

  // ---- Phase A: 8 chunks of 64 channels, double-buffered
  for (int ck = 0; ck < 8; ++ck) {
    __syncthreads();                       // chunk ck's buffer is ready
    f32x4 nv0, nv1;
    if (ck < 7) {                          // issue next chunk's loads early
      const float* src = xb + (size_t)(ck+1)*64*16384;
      nv0 = *(const f32x4*)src;
      nv1 = *(const f32x4*)(src + 16384);
    }
    const char* Xb = (ck & 1) ? Xs1 : Xs0;
    #pragma unroll
    for (int ks = 0; ks < 2; ++ks) {
      const int kbl = ks*4 + g;            // kb within chunk, 0..7
      const int kbg = ck*8 + kbl;          // global kb, 0..63
      f16x8 bf[4];
      #pragma unroll
      for (int pt = 0; pt < 4; ++pt) {
        int p = pt*16 + r;
        bf[pt] = *(const f16x8*)(Xb + p*128 + ((kbl*16) ^ (SX(p)<<4)));
      }
      #pragma unroll
      for (int e = 0; e < 4; ++e) {
        f16x8 a = *(const f16x8*)(W1s + ((size_t)((e*64 + kbg)*128) + o0 + r)*8);
        #pragma unroll
        for (int pt = 0; pt < 4; ++pt)
          acc[e][pt] = __builtin_amdgcn_mfma_f32_16x16x32_f16(a, bf[pt], acc[e][pt], 0, 0, 0);
      }
    }
    if (ck < 7) {                          // write next chunk into other buffer
      char* dst = (ck & 1) ? Xs0 : Xs1;
      #pragma unroll
      for (int i = 0; i < 4; ++i) {
        int p = q*4 + i;
        f16x2 hv; hv[0] = (f16)nv0[i]; hv[1] = (f16)nv1[i];
        *(f16x2*)(dst + p*128 + ((4*cp) ^ (SX(p)<<4))) = hv;
      }
    }
  }

  // ---- Phase B: per expert chain
  f32x4 outacc = {0.f, 0.f, 0.f, 0.f};
  for (int e = 0; e < 4; ++e) {
    // H1 = relu(acc + b1) -> LDS [p][h]
    {
      const f32x4 bias = *(const f32x4*)(b1 + e*128 + o0 + g*4);
      const int ob = (o0 + g*4) * 2;       // byte col
      #pragma unroll
      for (int pt = 0; pt < 4; ++pt) {
        int p = pt*16 + r;
        f16x4 h;
        #pragma unroll
        for (int j = 0; j < 4; ++j) h[j] = (f16)fmaxf(acc[e][pt][j] + bias[j], 0.f);
        *(f16x4*)(H1t + p*256 + (ob ^ (SX(p)<<4))) = h;
      }
    }
    __syncthreads();

    // L2: H2 = relu(W2 @ H1 + b2); 12 fragments over 8 waves
    #pragma unroll
    for (int s = 0; s < 2; ++s) {
      int f = wave + s*8;
      if (f < 12) {
        int ot = f >> 2, pt = f & 3;
        int p = pt*16 + r;
        f32x4 acc2 = {0.f,0.f,0.f,0.f};
        #pragma unroll
        for (int ks = 0; ks < 4; ++ks) {
          int kb = ks*4 + g;
          f16x8 a  = *(const f16x8*)(W2s + (size_t)((e*16 + kb)*48 + ot*16 + r)*8);
          f16x8 bf = *(const f16x8*)(H1t + p*256 + ((kb*16) ^ (SX(p)<<4)));
          acc2 = __builtin_amdgcn_mfma_f32_16x16x32_f16(a, bf, acc2, 0, 0, 0);
        }
        const f32x4 bias = *(const f32x4*)(b2 + e*48 + ot*16 + g*4);
        const int ob = (ot*16 + g*4) * 2;
        f16x4 h;
        #pragma unroll
        for (int j = 0; j < 4; ++j) h[j] = (f16)fmaxf(acc2[j] + bias[j], 0.f);
        *(f16x4*)(H2t + p*128 + (ob ^ (SX(p)<<4))) = h;
      }
    }
    __syncthreads();

    // L3 + weighted combine (waves 0-3, pt = wave)
    if (wave < 4) {
      const int pt = wave;
      int p = pt*16 + r;
      f32x4 acc3 = {0.f,0.f,0.f,0.f};
      #pragma unroll
      for (int ks = 0; ks < 2; ++ks) {
        int kb = ks*4 + g;
        f16x8 a  = *(const f16x8*)(W3s + (size_t)((e*8 + kb)*16 + r)*8);
        f16x8 bf = *(const f16x8*)(H2t + p*128 + ((kb*16) ^ (SX(p)<<4)));
        acc3 = __builtin_amdgcn_mfma_f32_16x16x32_f16(a, bf, acc3, 0, 0, 0);
      }
      const float w_e = wgt[(b*4 + m)*4 + e];
      const f32x4 bias = *(const f32x4*)(b3 + e*16 + g*4);
      #pragma unroll
      for (int j = 0; j < 4; ++j) outacc[j] += w_e * (acc3[j] + bias[j]);
    }
    // H1t rewrite (next e) is fenced by the post-L2 barrier; H2t rewrite by post-H1 barrier.
  }

  // ---- store out[b][o][m][n]
  if (wave < 4) {
    const int pt = wave;
    #pragma unroll
    for (int reg = 0; reg < 4; ++reg) {
      int o = g*4 + reg;
      out[(((size_t)b*16 + o)*4 + m)*4096 + (size_t)tile*64 + pt*16 + r] = outacc[reg];
    }
  }
}

// ---------------- launcher ----------------
extern "C" void kernel_launch(void* const* d_in, const int* in_sizes, int n_in,
                              void* d_out, int out_size, void* d_ws, size_t ws_size,
                              hipStream_t stream) {
  const float* x   = (const float*)d_in[0];
  const float* W1  = (const float*)d_in[1];
  const float* b1  = (const float*)d_in[2];
  const float* W2  = (const float*)d_in[3];
  const float* b2  = (const float*)d_in[4];
  const float* W3  = (const float*)d_in[5];
  const float* b3  = (const float*)d_in[6];
  const float* Wg1 = (const float*)d_in[7];
  const float* bg1 = (const float*)d_in[8];
  const float* Wg2 = (const float*)d_in[9];
  const float* bg2 = (const float*)d_in[10];
  float* out = (float*)d_out;

  char* ws = (char*)d_ws;
  float* pooled = (float*)ws;                         // 131072 B  [b][c][m]
  float* wgt    = (float*)(ws + 131072);              //   1024 B  [b][m][e]
  f16* W1s = (f16*)(ws + 132096);                     // 524288 B
  f16* W2s = (f16*)(ws + 132096 + 524288);            //  49152 B
  f16* W3s = (f16*)(ws + 132096 + 524288 + 49152);    //   8192 B

  prep_kernel<<<(262144 + 24576 + 4096 + 255)/256, 256, 0, stream>>>(W1, W2, W3, W1s, W2s, W3s);
  pool_kernel<<<BDIM*CDIM*MDIM, 256, 0, stream>>>(x, pooled);
  gate_kernel<<<BDIM, 256, 0, stream>>>(pooled, Wg1, bg1, Wg2, bg2, wgt);
  moe_kernel<<<BDIM*MDIM*NTILES, 512, 0, stream>>>(x, W1s, W2s, W3s, b1, b2, b3, wgt, out);
}